// Round 7
// baseline (421.527 us; speedup 1.0000x reference)
//
#include <hip/hip_runtime.h>

typedef _Float16 half8 __attribute__((ext_vector_type(8)));
typedef _Float16 half4 __attribute__((ext_vector_type(4)));
typedef float f32x4 __attribute__((ext_vector_type(4)));

__device__ __forceinline__ float eluf(float x)   { return x > 0.f ? x : __expf(x) - 1.f; }
__device__ __forceinline__ float sigf(float x)   { return 1.f / (1.f + __expf(-x)); }
__device__ __forceinline__ float tanhff(float x) { float e = __expf(2.f * x); return 1.f - 2.f / (e + 1.f); }

__device__ __forceinline__ half8 cvt8(const float* __restrict__ p) {
  f32x4 v0 = *(const f32x4*)p;
  f32x4 v1 = *(const f32x4*)(p + 4);
  half8 r;
  r[0] = (_Float16)v0[0]; r[1] = (_Float16)v0[1]; r[2] = (_Float16)v0[2]; r[3] = (_Float16)v0[3];
  r[4] = (_Float16)v1[0]; r[5] = (_Float16)v1[1]; r[6] = (_Float16)v1[2]; r[7] = (_Float16)v1[3];
  return r;
}
#define MFMA(a, b, c) __builtin_amdgcn_mfma_f32_16x16x32_f16(a, b, c, 0, 0, 0)

// ---------------- done normalize -> per-t u64 bitmask -----------------------
__global__ void k_done(const unsigned char* __restrict__ raw,
                       unsigned long long* __restrict__ dmask) {
  __shared__ int flagNon0;
  __shared__ int flagAt0;
  if (threadIdx.x == 0) { flagNon0 = 0; flagAt0 = 0; }
  __syncthreads();
  int l0 = 0, l1 = 0;
  for (int i = threadIdx.x; i < 16384; i += 256) {
    if (raw[i]) { if (i & 3) l0 = 1; else l1 = 1; }
  }
  if (l0) atomicOr(&flagNon0, 1);
  if (l1) atomicOr(&flagAt0, 1);
  __syncthreads();
  int mode = (flagNon0 && flagAt0) ? 0 : (flagAt0 ? 1 : (flagNon0 ? 2 : 0));
  const int t = threadIdx.x;           // 256 threads = 256 t
  unsigned long long m = 0ULL;
  for (int b = 0; b < 64; ++b) {
    int i = t * 64 + b;
    bool v;
    if (mode == 0)      v = raw[i] != 0;
    else if (mode == 1) v = ((const int*)raw)[i] != 0;
    else                v = (((const float*)raw)[i] != 0.f);
    if (v) m |= (1ULL << b);
  }
  dmask[t] = m;
}

// ---------------- conv stack + readin + xgates (MFMA) -----------------------
// block = (t, b-half) = 32 samples, 512 threads / 8 waves; 71.5 KB LDS
// -> 2 blocks/CU, 512 blocks cover all 256 CUs.  (unchanged from round 6)
__global__ __launch_bounds__(512, 4) void k_conv(
    const float* __restrict__ inp,
    const float* __restrict__ c1w, const float* __restrict__ c1b,
    const float* __restrict__ c2w, const float* __restrict__ c2b,
    const float* __restrict__ c3w, const float* __restrict__ c3b,
    const float* __restrict__ riw, const float* __restrict__ rib,
    const float* __restrict__ wih, const float* __restrict__ bih,
    const float* __restrict__ bhh,
    _Float16* __restrict__ xgh)   // [256 t][512 gate][64 b] f16
{
  extern __shared__ char L[];
  _Float16* imgW = (_Float16*)L;                // [8][243] f16  3888 B (pad 3904)
  _Float16* a1W  = (_Float16*)(L + 3904);       // [8][1152] f16 18432 B
  _Float16* ic2  = (_Float16*)(L + 22336);      // [64][320] f16 (padded, swizzled) 40960 B
  _Float16* a2   = (_Float16*)(L + 63296);      // [32][128] f16 (swizzled) 8192 B
  _Float16* ft   = (_Float16*)(L + 22336);      // overlay: ic2 dead after conv2
  _Float16* yb   = (_Float16*)(L + 30528);      // overlay, [32][128]

  const int tid  = threadIdx.x;
  const int lane = tid & 63;
  const int wv   = tid >> 6;        // wave 0..7
  const int lr   = lane & 15;
  const int lg   = lane >> 4;
  const int t    = blockIdx.x >> 1;
  const int bh   = blockIdx.x & 1;  // b-half: samples bh*32 .. +31

  // conv1 weights in registers: lane owns o = lane&31 (halves duplicate)
  const int o1 = lane & 31;
  const int hw = lane >> 5;
  float w1r[27];
  #pragma unroll
  for (int k = 0; k < 27; ++k) w1r[k] = c1w[o1 * 27 + k];
  const float b1 = c1b[o1];

  // zero img+a1 region (borders must stay zero across chunks/reps)
  for (int i = tid; i < 22336 / 4; i += 512) ((unsigned*)L)[i] = 0u;

  // conv2 B-frags: wave -> (mt2 = wv>>1, nt2 = wv&1); cols o = nt2*16+lr.
  const int nt2 = wv & 1, mt2 = wv >> 1;
  half8 B2[9];
  #pragma unroll
  for (int kt = 0; kt < 9; ++kt)
    B2[kt] = cvt8(c2w + (nt2 * 16 + lr) * 288 + kt * 32 + lg * 8);

  __syncthreads();

  _Float16* img = imgW + wv * 243;
  _Float16* a1  = a1W + wv * 1152;

  for (int ch = 0; ch < 2; ++ch) {        // 2 chunks x 16 samples
    __syncthreads();                      // prev chunk's GEMM reads done
    for (int rep = 0; rep < 2; ++rep) {   // 2 samples per wave per chunk
      const int sl = wv * 2 + rep;        // sample-local in chunk
      const int n  = t * 64 + bh * 32 + ch * 16 + sl;
      const float* src = inp + n * 147;
      // img[c][p+1][q+1] = inp[n][q][p][c]; linear src (i == q*21+p*3+c)
      for (int i = lane; i < 147; i += 64) {
        int c = i % 3, p = (i / 3) % 7, q = i / 21;
        img[(c * 9 + p + 1) * 9 + q + 1] = (_Float16)src[i];
      }
      // conv1 direct: lane owns o1 for all 16 positions; wave-private data.
      #pragma unroll 2
      for (int it = 0; it < 8; ++it) {
        int pos = it * 2 + hw;
        int p = pos >> 2, q = pos & 3;
        float acc = b1;
        #pragma unroll
        for (int i = 0; i < 3; ++i)
          #pragma unroll
          for (int dp = 0; dp < 3; ++dp)
            #pragma unroll
            for (int dq = 0; dq < 3; ++dq)
              acc += (float)img[(i * 9 + 2 * p + dp) * 9 + 2 * q + dq] * w1r[i * 9 + dp * 3 + dq];
        a1[(o1 * 6 + p + 1) * 6 + q + 1] = (_Float16)eluf(acc);
      }
      // im2col rows m = sl*4 + pos (row stride 320 keeps 64-span XOR in-row)
      for (int rr = 0; rr < 18; ++rr) {
        int i2 = rr * 64 + lane;              // 4 pos x 288 k
        int k = i2 % 288, pos = i2 / 288;
        int p = pos >> 1, q = pos & 1;
        int i = k / 9, r9 = k % 9, dp = r9 / 3, dq = r9 % 3;
        _Float16 v = a1[(i * 6 + 2 * p + dp) * 6 + 2 * q + dq];
        int m = sl * 4 + pos;
        ic2[m * 320 + (k ^ ((m & 7) << 3))] = v;
      }
    }
    __syncthreads();
    // conv2 GEMM for this chunk: M=64 (16s x 4pos), K=288, N=32
    {
      float bb = c2b[nt2 * 16 + lr];
      f32x4 acc; acc[0] = bb; acc[1] = bb; acc[2] = bb; acc[3] = bb;
      const int row = mt2 * 16 + lr;
      #pragma unroll
      for (int kt = 0; kt < 9; ++kt) {
        half8 a = *(const half8*)(ic2 + row * 320 + ((kt * 32 + lg * 8) ^ ((row & 7) << 3)));
        acc = MFMA(a, B2[kt], acc);
      }
      #pragma unroll
      for (int r = 0; r < 4; ++r) {
        int m = mt2 * 16 + lg * 4 + r;            // (s2, pos)
        int s2 = m >> 2, pos = m & 3;
        int arow = ch * 16 + s2;                  // 0..31
        int col = (nt2 * 16 + lr) * 4 + pos;      // a2 col = o*4+pos
        a2[arow * 128 + (col ^ ((arow & 7) << 3))] = (_Float16)eluf(acc[r]);
      }
    }
  }
  __syncthreads();   // last conv2 GEMM reads of ic2 done -> ft/yb may reuse it

  // conv3 GEMM: M=32, K=128 (i*4+pos), N=128; wave = n-tile
  {
    half8 B3[4];
    #pragma unroll
    for (int kt = 0; kt < 4; ++kt) {
      half8 b;
      #pragma unroll
      for (int e = 0; e < 8; ++e) {
        int k = kt * 32 + lg * 8 + e;
        int i = k >> 2, pos = k & 3;
        int widx = 4 + (pos >> 1) * 3 + (pos & 1);   // taps {4,5,7,8}
        b[e] = (_Float16)c3w[(wv * 16 + lr) * 288 + i * 9 + widx];
      }
      B3[kt] = b;
    }
    float bb = c3b[wv * 16 + lr];
    #pragma unroll
    for (int mt = 0; mt < 2; ++mt) {
      f32x4 acc; acc[0] = bb; acc[1] = bb; acc[2] = bb; acc[3] = bb;
      const int row = mt * 16 + lr;
      #pragma unroll
      for (int kt = 0; kt < 4; ++kt) {
        half8 a = *(const half8*)(a2 + row * 128 + ((kt * 32 + lg * 8) ^ ((row & 7) << 3)));
        acc = MFMA(a, B3[kt], acc);
      }
      #pragma unroll
      for (int r = 0; r < 4; ++r) {
        int m = mt * 16 + lg * 4 + r;
        ft[m * 128 + ((wv * 16 + lr) ^ ((m & 7) << 3))] = (_Float16)eluf(acc[r]);
      }
    }
  }
  __syncthreads();

  // GEMM1: y = ft @ riw^T + rib
  {
    half8 R1[4];
    #pragma unroll
    for (int kt = 0; kt < 4; ++kt)
      R1[kt] = cvt8(riw + (wv * 16 + lr) * 128 + kt * 32 + lg * 8);
    float bb = rib[wv * 16 + lr];
    #pragma unroll
    for (int mt = 0; mt < 2; ++mt) {
      f32x4 acc; acc[0] = bb; acc[1] = bb; acc[2] = bb; acc[3] = bb;
      const int row = mt * 16 + lr;
      #pragma unroll
      for (int kt = 0; kt < 4; ++kt) {
        half8 a = *(const half8*)(ft + row * 128 + ((kt * 32 + lg * 8) ^ ((row & 7) << 3)));
        acc = MFMA(a, R1[kt], acc);
      }
      #pragma unroll
      for (int r = 0; r < 4; ++r) {
        int m = mt * 16 + lg * 4 + r;
        yb[m * 128 + ((wv * 16 + lr) ^ ((m & 7) << 3))] = (_Float16)acc[r];
      }
    }
  }
  __syncthreads();

  // GEMM2: xg = y @ wih^T + (bih + bhh); N=512, wave owns gates ty*128+16wv+lr
  {
    half8 W2f[4][4];   // [kt][ty]
    float bg[4];
    #pragma unroll
    for (int ty = 0; ty < 4; ++ty) {
      int g = ty * 128 + wv * 16 + lr;
      bg[ty] = bih[g] + bhh[g];
      #pragma unroll
      for (int kt = 0; kt < 4; ++kt)
        W2f[kt][ty] = cvt8(wih + g * 128 + kt * 32 + lg * 8);
    }
    #pragma unroll
    for (int mt = 0; mt < 2; ++mt) {
      const int row = mt * 16 + lr;
      half8 a[4];
      #pragma unroll
      for (int kt = 0; kt < 4; ++kt)
        a[kt] = *(const half8*)(yb + row * 128 + ((kt * 32 + lg * 8) ^ ((row & 7) << 3)));
      #pragma unroll
      for (int ty = 0; ty < 4; ++ty) {
        f32x4 acc; acc[0] = bg[ty]; acc[1] = bg[ty]; acc[2] = bg[ty]; acc[3] = bg[ty];
        #pragma unroll
        for (int kt = 0; kt < 4; ++kt) acc = MFMA(a[kt], W2f[kt][ty], acc);
        int g = ty * 128 + wv * 16 + lr;
        half4 h4;
        h4[0] = (_Float16)acc[0]; h4[1] = (_Float16)acc[1];
        h4[2] = (_Float16)acc[2]; h4[3] = (_Float16)acc[3];
        *(half4*)(xgh + ((size_t)t * 512 + g) * 64 + bh * 32 + mt * 16 + lg * 4) = h4;
      }
    }
  }
}

// ---------------- windowed LSTM (16 steps, MFMA) + readout ------------------
// block = one t (64 samples), 1024 threads / 16 waves, grid 256 lockstep
// (round-3 t-map for L2 xg reuse; f16 xg keeps XCD window at 2.1 MB < 4 MB L2
// so 4 waves/SIMD occupancy is safe — round-5's thrash was the f32 4.2 MB).
// wave = (mg = wv>>3 sample-half, wc = wv&7 cell-group); per-wave 2 m-tiles.
__global__ __launch_bounds__(1024, 4) void k_lstm(
    const float* __restrict__ whh, const float* __restrict__ bih,
    const float* __restrict__ bhh, const _Float16* __restrict__ xgh,
    const unsigned long long* __restrict__ dmask,
    const float* __restrict__ row_, const float* __restrict__ rob,
    float* __restrict__ out)
{
  __shared__ _Float16 H[2][64 * 128];   // 32 KB, XOR-swizzled rows

  const int tid  = threadIdx.x;
  const int lane = tid & 63;
  const int wv   = tid >> 6;            // 0..15
  const int wc   = wv & 7;              // cell group: cells wc*16 + lr
  const int mg   = wv >> 3;             // sample half: mt = mg*2 + m
  const int lr   = lane & 15, lg = lane >> 4;
  // XCD-chunked: XCD x gets t in [32x, 32x+32) -> window overlap shares L2
  const int t = ((blockIdx.x & 7) << 5) + (blockIdx.x >> 3);

  // w_hh B-frags: [kt][ty], gate g = ty*128 + wc*16 + lr
  half8 Wf[4][4];
  float b0[4];
  #pragma unroll
  for (int ty = 0; ty < 4; ++ty) {
    int g = ty * 128 + wc * 16 + lr;
    b0[ty] = bih[g] + bhh[g];
    #pragma unroll
    for (int kt = 0; kt < 4; ++kt)
      Wf[kt][ty] = cvt8(whh + g * 128 + kt * 32 + lg * 8);
  }

  for (int i = tid; i < 64 * 128 / 2; i += 1024) ((unsigned*)H[0])[i] = 0u;

  float cc[2][4];   // [m][r]: sample (mg*2+m)*16 + lg*4 + r, cell wc*16+lr
  #pragma unroll
  for (int m = 0; m < 2; ++m)
    #pragma unroll
    for (int r = 0; r < 4; ++r) cc[m][r] = 0.f;

  half4 pfA[4][2], pfB[4][2];   // [ty][m] xg prefetch (static indices only)

#define PF_LOAD(PF, TS1) do {                                                  \
    if ((TS1) >= 0) {                                                          \
      const _Float16* xb1 = xgh + (size_t)(TS1) * 32768;                       \
      _Pragma("unroll") for (int ty = 0; ty < 4; ++ty)                         \
        _Pragma("unroll") for (int m = 0; m < 2; ++m)                          \
          PF[ty][m] = *(const half4*)(xb1 + (ty * 128 + wc * 16 + lr) * 64     \
                                          + (mg * 2 + m) * 16 + lg * 4);       \
    }                                                                          \
  } while (0)

#define LSTM_STEP(ST, PFU, PFL) do {                                           \
    const int ts_ = t + (ST) - 15;                                             \
    _Float16* Hr = H[(ST) & 1];                                                \
    _Float16* Hw = H[((ST) & 1) ^ 1];                                          \
    __syncthreads();                                                           \
    if ((ST) < 15) PF_LOAD(PFL, ts_ + 1);                                      \
    const bool hasX = (ts_ >= 0);                                              \
    const unsigned long long wm =                                              \
        ((ST) < 15 && ts_ + 1 >= 0) ? dmask[ts_ + 1] : 0ULL;                   \
    _Pragma("unroll") for (int m = 0; m < 2; ++m) {                            \
      const int mt = mg * 2 + m;                                               \
      const int rowA = mt * 16 + lr;                                           \
      half8 afr[4];                                                            \
      _Pragma("unroll") for (int kt = 0; kt < 4; ++kt)                         \
        afr[kt] = *(const half8*)(Hr + rowA * 128 +                            \
                                  ((kt * 32 + lg * 8) ^ ((rowA & 7) << 3)));   \
      f32x4 acc[4];                                                            \
      if (hasX) {                                                              \
        _Pragma("unroll") for (int ty = 0; ty < 4; ++ty) {                     \
          half4 p = PFU[ty][m];                                                \
          acc[ty][0] = (float)p[0]; acc[ty][1] = (float)p[1];                  \
          acc[ty][2] = (float)p[2]; acc[ty][3] = (float)p[3];                  \
        }                                                                      \
      } else {                                                                 \
        _Pragma("unroll") for (int ty = 0; ty < 4; ++ty) {                     \
          acc[ty][0] = b0[ty]; acc[ty][1] = b0[ty];                            \
          acc[ty][2] = b0[ty]; acc[ty][3] = b0[ty];                            \
        }                                                                      \
      }                                                                        \
      _Pragma("unroll") for (int ty = 0; ty < 4; ++ty)                         \
        _Pragma("unroll") for (int kt = 0; kt < 4; ++kt)                       \
          acc[ty] = MFMA(afr[kt], Wf[kt][ty], acc[ty]);                        \
      _Pragma("unroll") for (int r = 0; r < 4; ++r) {                          \
        const int s_ = mt * 16 + lg * 4 + r;                                   \
        const bool d = (wm >> s_) & 1ULL;                                      \
        float iv = sigf(acc[0][r]);                                            \
        float fv = sigf(acc[1][r]);                                            \
        float gv = tanhff(acc[2][r]);                                          \
        float ov = sigf(acc[3][r]);                                            \
        float cn = fmaf(fv, cc[m][r], iv * gv);                                \
        float hn = ov * tanhff(cn);                                            \
        cc[m][r] = d ? 0.f : cn;                                               \
        Hw[s_ * 128 + ((wc * 16 + lr) ^ ((s_ & 7) << 3))] =                    \
            (_Float16)(d ? 0.f : hn);                                          \
      }                                                                        \
    }                                                                          \
  } while (0)

  PF_LOAD(pfA, t - 15);       // prefetch step 0
  for (int s2 = 0; s2 < 8; ++s2) {
    LSTM_STEP(2 * s2,     pfA, pfB);
    LSTM_STEP(2 * s2 + 1, pfB, pfA);
  }
#undef LSTM_STEP
#undef PF_LOAD
  __syncthreads();

  // readout: out = h_final @ row_^T + rob  (h_final in H[0] after st=15)
  half8 R[4];
  #pragma unroll
  for (int kt = 0; kt < 4; ++kt)
    R[kt] = cvt8(row_ + (wc * 16 + lr) * 128 + kt * 32 + lg * 8);
  float rb2 = rob[wc * 16 + lr];
  #pragma unroll
  for (int m = 0; m < 2; ++m) {
    const int mt = mg * 2 + m;
    const int row = mt * 16 + lr;
    f32x4 acc; acc[0] = rb2; acc[1] = rb2; acc[2] = rb2; acc[3] = rb2;
    #pragma unroll
    for (int kt = 0; kt < 4; ++kt) {
      half8 a = *(const half8*)(H[0] + row * 128 + ((kt * 32 + lg * 8) ^ ((row & 7) << 3)));
      acc = MFMA(a, R[kt], acc);
    }
    #pragma unroll
    for (int r = 0; r < 4; ++r) {
      int s = mt * 16 + lg * 4 + r;
      out[(size_t)(t * 64 + s) * 128 + wc * 16 + lr] = acc[r];
    }
  }
}

extern "C" void kernel_launch(void* const* d_in, const int* in_sizes, int n_in,
                              void* d_out, int out_size, void* d_ws, size_t ws_size,
                              hipStream_t stream) {
  const float* inp = (const float*)d_in[0];
  const void*  don = d_in[1];
  const float* c1w = (const float*)d_in[2];
  const float* c1b = (const float*)d_in[3];
  const float* c2w = (const float*)d_in[4];
  const float* c2b = (const float*)d_in[5];
  const float* c3w = (const float*)d_in[6];
  const float* c3b = (const float*)d_in[7];
  const float* riw = (const float*)d_in[8];
  const float* rib = (const float*)d_in[9];
  const float* wih = (const float*)d_in[10];
  const float* whh = (const float*)d_in[11];
  const float* bih = (const float*)d_in[12];
  const float* bhh = (const float*)d_in[13];
  const float* row_ = (const float*)d_in[14];
  const float* rob = (const float*)d_in[15];

  unsigned long long* dmask = (unsigned long long*)d_ws;     // 2 KB
  _Float16* xgh = (_Float16*)((char*)d_ws + 16384);          // 16.8 MB f16

  (void)hipFuncSetAttribute((const void*)k_conv,
                            hipFuncAttributeMaxDynamicSharedMemorySize, 71488);

  k_done<<<1, 256, 0, stream>>>((const unsigned char*)don, dmask);
  k_conv<<<512, 512, 71488, stream>>>(inp, c1w, c1b, c2w, c2b, c3w, c3b,
                                      riw, rib, wih, bih, bhh, xgh);
  k_lstm<<<256, 1024, 0, stream>>>(whh, bih, bhh, xgh, dmask, row_, rob,
                                   (float*)d_out);
}

// Round 8
// 382.140 us; speedup vs baseline: 1.1031x; 1.1031x over previous
//
#include <hip/hip_runtime.h>

typedef _Float16 half8 __attribute__((ext_vector_type(8)));
typedef _Float16 half4 __attribute__((ext_vector_type(4)));
typedef float f32x4 __attribute__((ext_vector_type(4)));

__device__ __forceinline__ float eluf(float x)   { return x > 0.f ? x : __expf(x) - 1.f; }
__device__ __forceinline__ float sigf(float x)   { return 1.f / (1.f + __expf(-x)); }
__device__ __forceinline__ float tanhff(float x) { float e = __expf(2.f * x); return 1.f - 2.f / (e + 1.f); }

__device__ __forceinline__ half8 cvt8(const float* __restrict__ p) {
  f32x4 v0 = *(const f32x4*)p;
  f32x4 v1 = *(const f32x4*)(p + 4);
  half8 r;
  r[0] = (_Float16)v0[0]; r[1] = (_Float16)v0[1]; r[2] = (_Float16)v0[2]; r[3] = (_Float16)v0[3];
  r[4] = (_Float16)v1[0]; r[5] = (_Float16)v1[1]; r[6] = (_Float16)v1[2]; r[7] = (_Float16)v1[3];
  return r;
}
#define MFMA(a, b, c) __builtin_amdgcn_mfma_f32_16x16x32_f16(a, b, c, 0, 0, 0)

// ---------------- done normalize -> per-t u64 bitmask (parallel) ------------
__global__ __launch_bounds__(256) void k_done(const unsigned char* __restrict__ raw,
                                              unsigned long long* __restrict__ dmask) {
  __shared__ int f0, f1;
  if (threadIdx.x == 0) { f0 = 0; f1 = 0; }
  __syncthreads();
  int l0 = 0, l1 = 0;
  for (int i = threadIdx.x; i < 16384; i += 256)    // same scan window as verified version
    if (raw[i]) { if (i & 3) l0 = 1; else l1 = 1; }
  if (l0) atomicOr(&f0, 1);
  if (l1) atomicOr(&f1, 1);
  __syncthreads();
  int mode = (f0 && f1) ? 0 : (f1 ? 1 : (f0 ? 2 : 0));
  const int t = blockIdx.x;
  if (threadIdx.x < 64) {
    int i = t * 64 + threadIdx.x;
    bool v;
    if (mode == 0)      v = raw[i] != 0;
    else if (mode == 1) v = ((const int*)raw)[i] != 0;
    else                v = (((const float*)raw)[i] != 0.f);
    unsigned long long m = __ballot(v);
    if (threadIdx.x == 0) dmask[t] = m;
  }
}

// ---------------- conv stack + readin + xgates (all-MFMA) -------------------
// block = (t, b-half) = 32 samples, 512 threads / 8 waves; 60.5 KB LDS.
// conv1: im2col (K=27 pad 32) from global + 1 MFMA/tile -> a1t channel-last.
// conv2: 9 tap-GEMMs (K=32) reading a1t directly (no 288-im2col).
__global__ __launch_bounds__(512, 4) void k_conv(
    const float* __restrict__ inp,
    const float* __restrict__ c1w, const float* __restrict__ c1b,
    const float* __restrict__ c2w, const float* __restrict__ c2b,
    const float* __restrict__ c3w, const float* __restrict__ c3b,
    const float* __restrict__ riw, const float* __restrict__ rib,
    const float* __restrict__ wih, const float* __restrict__ bih,
    const float* __restrict__ bhh,
    _Float16* __restrict__ xgh)   // [256 t][512 gate][64 b] f16
{
  extern __shared__ char L[];
  unsigned*  LUT32 = (unsigned*)L;              // [32] u32, 128 B
  _Float16*  ic1   = (_Float16*)(L + 128);      // [256][32] f16 swz, 16384 B
  _Float16*  a1t   = (_Float16*)(L + 16512);    // [16][1160] f16 (36 xy x 32 ch, pad), 37120 B
  _Float16*  a2    = (_Float16*)(L + 53632);    // [32][128] f16 swz, 8192 B  (end 61824)
  _Float16*  ft    = (_Float16*)(L + 128);      // overlay (ic1/a1t dead)
  _Float16*  yb    = (_Float16*)(L + 8320);     // overlay

  const int tid  = threadIdx.x;
  const int lane = tid & 63;
  const int wv   = tid >> 6;        // 0..7
  const int lr   = lane & 15;
  const int lg   = lane >> 4;
  const int t    = blockIdx.x >> 1;
  const int bh   = blockIdx.x & 1;

  const int ntl  = wv & 1;          // n-tile for conv1/conv2 (o = ntl*16+lr)
  const int mq   = wv >> 1;         // m-group
  const int o1   = ntl * 16 + lr;

  // LUT32: k -> (c,dp,dq) packed; 0xFFFFFFFF for pad k>=27
  if (tid < 32) {
    unsigned v = 0xFFFFFFFFu;
    if (tid < 27) { int c = tid / 9, r9 = tid % 9; v = (unsigned)(c | ((r9 / 3) << 8) | ((r9 % 3) << 16)); }
    LUT32[tid] = v;
  }

  // conv1 B-frag: o = o1, k = lg*8+e (guard k<27)
  half8 B1;
  #pragma unroll
  for (int e = 0; e < 8; ++e) {
    int k = lg * 8 + e;
    B1[e] = (_Float16)((k < 27) ? c1w[o1 * 27 + k] : 0.f);
  }
  const float b1o = c1b[o1];

  // conv2 tap B-frags: B2t[tap][o1][i = lg*8+e] = c2w[o1][i][dp][dq]
  half8 B2t[9];
  #pragma unroll
  for (int tap = 0; tap < 9; ++tap) {
    half8 b;
    #pragma unroll
    for (int e = 0; e < 8; ++e)
      b[e] = (_Float16)c2w[o1 * 288 + (lg * 8 + e) * 9 + tap];
    B2t[tap] = b;
  }
  const float b2o = c2b[o1];

  for (int ch = 0; ch < 2; ++ch) {        // 2 chunks x 16 samples
    __syncthreads();                      // prev phase readers done
    // zero a1t (borders must be 0)
    for (int i = tid; i < 18560 / 2; i += 512) ((unsigned*)a1t)[i] = 0u;
    // build ic1: rows = s*16+pos (256), K=32 (27 valid), from global input
    {
      const size_t n0 = (size_t)(t * 64 + bh * 32 + ch * 16) * 147;
      #pragma unroll
      for (int j = 0; j < 16; ++j) {
        int e = tid + j * 512;            // 0..8191
        int row = e >> 5, k = e & 31;
        int s = row >> 4, pos = row & 15;
        int p = pos >> 2, q = pos & 3;
        unsigned lut = LUT32[k];
        float v = 0.f;
        if (lut != 0xFFFFFFFFu) {
          int c = lut & 0xFF, dp = (lut >> 8) & 0xFF, dq = (lut >> 16) & 0xFF;
          int pp = 2 * p + dp - 1, qq = 2 * q + dq - 1;
          if ((unsigned)pp < 7u && (unsigned)qq < 7u)
            v = inp[n0 + s * 147 + qq * 21 + pp * 3 + c];
        }
        ic1[row * 32 + (k ^ ((row & 3) << 3))] = (_Float16)v;
      }
    }
    __syncthreads();
    // conv1 GEMM: M=256 (16 mtiles), N=32, K=32; wave (mq, ntl) does 4 mtiles
    #pragma unroll
    for (int mi = 0; mi < 4; ++mi) {
      const int mtile = mq * 4 + mi;
      const int rowA  = mtile * 16 + lr;
      half8 a = *(const half8*)(ic1 + rowA * 32 + ((lg * 8) ^ ((rowA & 3) << 3)));
      f32x4 acc; acc[0] = b1o; acc[1] = b1o; acc[2] = b1o; acc[3] = b1o;
      acc = MFMA(a, B1, acc);
      #pragma unroll
      for (int r = 0; r < 4; ++r) {
        int m1 = mtile * 16 + lg * 4 + r;
        int s = m1 >> 4, pos = m1 & 15;
        int p = pos >> 2, q = pos & 3;
        int xy = (p + 1) * 6 + (q + 1);
        a1t[s * 1160 + xy * 32 + (o1 ^ ((xy & 3) << 3))] = (_Float16)eluf(acc[r]);
      }
    }
    __syncthreads();
    // conv2: 9 tap-GEMMs, M=64 (4 mtiles; wave mq does mtile=mq), N=32, K=32/tap
    {
      f32x4 acc; acc[0] = b2o; acc[1] = b2o; acc[2] = b2o; acc[3] = b2o;
      const int rowm = mq * 16 + lr;
      const int s2 = rowm >> 2, pos2 = rowm & 3;
      const int p2 = pos2 >> 1, q2 = pos2 & 1;
      #pragma unroll
      for (int tap = 0; tap < 9; ++tap) {
        const int dp = tap / 3, dq = tap % 3;           // compile-time
        const int xy2 = (2 * p2 + dp) * 6 + (2 * q2 + dq);
        half8 a = *(const half8*)(a1t + s2 * 1160 + xy2 * 32 + ((lg * 8) ^ ((xy2 & 3) << 3)));
        acc = MFMA(a, B2t[tap], acc);
      }
      #pragma unroll
      for (int r = 0; r < 4; ++r) {
        int m = mq * 16 + lg * 4 + r;                   // (s2, pos)
        int s2w = m >> 2, pos = m & 3;
        int arow = ch * 16 + s2w;                       // 0..31
        int col = o1 * 4 + pos;                         // a2 col = o*4+pos
        a2[arow * 128 + (col ^ ((arow & 7) << 3))] = (_Float16)eluf(acc[r]);
      }
    }
  }
  __syncthreads();   // a2 complete; ic1/a1t regions now free for ft/yb

  // conv3 GEMM: M=32, K=128 (i*4+pos), N=128; wave = n-tile  (verified R6 code)
  {
    half8 B3[4];
    #pragma unroll
    for (int kt = 0; kt < 4; ++kt) {
      half8 b;
      #pragma unroll
      for (int e = 0; e < 8; ++e) {
        int k = kt * 32 + lg * 8 + e;
        int i = k >> 2, pos = k & 3;
        int widx = 4 + (pos >> 1) * 3 + (pos & 1);   // taps {4,5,7,8}
        b[e] = (_Float16)c3w[(wv * 16 + lr) * 288 + i * 9 + widx];
      }
      B3[kt] = b;
    }
    float bb = c3b[wv * 16 + lr];
    #pragma unroll
    for (int mt = 0; mt < 2; ++mt) {
      f32x4 acc; acc[0] = bb; acc[1] = bb; acc[2] = bb; acc[3] = bb;
      const int row = mt * 16 + lr;
      #pragma unroll
      for (int kt = 0; kt < 4; ++kt) {
        half8 a = *(const half8*)(a2 + row * 128 + ((kt * 32 + lg * 8) ^ ((row & 7) << 3)));
        acc = MFMA(a, B3[kt], acc);
      }
      #pragma unroll
      for (int r = 0; r < 4; ++r) {
        int m = mt * 16 + lg * 4 + r;
        ft[m * 128 + ((wv * 16 + lr) ^ ((m & 7) << 3))] = (_Float16)eluf(acc[r]);
      }
    }
  }
  __syncthreads();

  // GEMM1: y = ft @ riw^T + rib
  {
    half8 R1[4];
    #pragma unroll
    for (int kt = 0; kt < 4; ++kt)
      R1[kt] = cvt8(riw + (wv * 16 + lr) * 128 + kt * 32 + lg * 8);
    float bb = rib[wv * 16 + lr];
    #pragma unroll
    for (int mt = 0; mt < 2; ++mt) {
      f32x4 acc; acc[0] = bb; acc[1] = bb; acc[2] = bb; acc[3] = bb;
      const int row = mt * 16 + lr;
      #pragma unroll
      for (int kt = 0; kt < 4; ++kt) {
        half8 a = *(const half8*)(ft + row * 128 + ((kt * 32 + lg * 8) ^ ((row & 7) << 3)));
        acc = MFMA(a, R1[kt], acc);
      }
      #pragma unroll
      for (int r = 0; r < 4; ++r) {
        int m = mt * 16 + lg * 4 + r;
        yb[m * 128 + ((wv * 16 + lr) ^ ((m & 7) << 3))] = (_Float16)acc[r];
      }
    }
  }
  __syncthreads();

  // GEMM2: xg = y @ wih^T + (bih + bhh); N=512
  {
    half8 W2f[4][4];   // [kt][ty]
    float bg[4];
    #pragma unroll
    for (int ty = 0; ty < 4; ++ty) {
      int g = ty * 128 + wv * 16 + lr;
      bg[ty] = bih[g] + bhh[g];
      #pragma unroll
      for (int kt = 0; kt < 4; ++kt)
        W2f[kt][ty] = cvt8(wih + g * 128 + kt * 32 + lg * 8);
    }
    #pragma unroll
    for (int mt = 0; mt < 2; ++mt) {
      const int row = mt * 16 + lr;
      half8 a[4];
      #pragma unroll
      for (int kt = 0; kt < 4; ++kt)
        a[kt] = *(const half8*)(yb + row * 128 + ((kt * 32 + lg * 8) ^ ((row & 7) << 3)));
      #pragma unroll
      for (int ty = 0; ty < 4; ++ty) {
        f32x4 acc; acc[0] = bg[ty]; acc[1] = bg[ty]; acc[2] = bg[ty]; acc[3] = bg[ty];
        #pragma unroll
        for (int kt = 0; kt < 4; ++kt) acc = MFMA(a[kt], W2f[kt][ty], acc);
        int g = ty * 128 + wv * 16 + lr;
        half4 h4;
        h4[0] = (_Float16)acc[0]; h4[1] = (_Float16)acc[1];
        h4[2] = (_Float16)acc[2]; h4[3] = (_Float16)acc[3];
        *(half4*)(xgh + ((size_t)t * 512 + g) * 64 + bh * 32 + mt * 16 + lg * 4) = h4;
      }
    }
  }
}

// ---------------- windowed LSTM (16 steps, MFMA) + readout ------------------
// block = one t, 1024 threads / 16 waves, grid 256.  PAIR-aware XCD swizzle:
// hypothesis = CP assigns 1024-thr blocks to XCDs in consecutive PAIRS, so
// xcd = (bid>>1)&7; idx = (bid>>4)*2+(bid&1) gives each XCD ts [32x,32x+32).
// (Bijective -> correctness-safe even if mapping hypothesis is wrong.)
__global__ __launch_bounds__(1024, 4) void k_lstm(
    const float* __restrict__ whh, const float* __restrict__ bih,
    const float* __restrict__ bhh, const _Float16* __restrict__ xgh,
    const unsigned long long* __restrict__ dmask,
    const float* __restrict__ row_, const float* __restrict__ rob,
    float* __restrict__ out)
{
  __shared__ _Float16 H[2][64 * 128];   // 32 KB, XOR-swizzled rows

  const int tid  = threadIdx.x;
  const int lane = tid & 63;
  const int wv   = tid >> 6;            // 0..15
  const int wc   = wv & 7;              // cell group: cells wc*16 + lr
  const int mg   = wv >> 3;             // sample half: mt = mg*2 + m
  const int lr   = lane & 15, lg = lane >> 4;
  const int xcd  = (blockIdx.x >> 1) & 7;
  const int idx  = ((blockIdx.x >> 4) << 1) | (blockIdx.x & 1);
  const int t    = (xcd << 5) + idx;

  // w_hh B-frags: [kt][ty], gate g = ty*128 + wc*16 + lr
  half8 Wf[4][4];
  float b0[4];
  #pragma unroll
  for (int ty = 0; ty < 4; ++ty) {
    int g = ty * 128 + wc * 16 + lr;
    b0[ty] = bih[g] + bhh[g];
    #pragma unroll
    for (int kt = 0; kt < 4; ++kt)
      Wf[kt][ty] = cvt8(whh + g * 128 + kt * 32 + lg * 8);
  }

  for (int i = tid; i < 64 * 128 / 2; i += 1024) ((unsigned*)H[0])[i] = 0u;

  float cc[2][4];   // [m][r]: sample (mg*2+m)*16 + lg*4 + r, cell wc*16+lr
  #pragma unroll
  for (int m = 0; m < 2; ++m)
    #pragma unroll
    for (int r = 0; r < 4; ++r) cc[m][r] = 0.f;

  half4 pfA[4][2], pfB[4][2];   // [ty][m] xg prefetch (static indices only)

#define PF_LOAD(PF, TS1) do {                                                  \
    if ((TS1) >= 0) {                                                          \
      const _Float16* xb1 = xgh + (size_t)(TS1) * 32768;                       \
      _Pragma("unroll") for (int ty = 0; ty < 4; ++ty)                         \
        _Pragma("unroll") for (int m = 0; m < 2; ++m)                          \
          PF[ty][m] = *(const half4*)(xb1 + (ty * 128 + wc * 16 + lr) * 64     \
                                          + (mg * 2 + m) * 16 + lg * 4);       \
    }                                                                          \
  } while (0)

#define LSTM_STEP(ST, PFU, PFL) do {                                           \
    const int ts_ = t + (ST) - 15;                                             \
    _Float16* Hr = H[(ST) & 1];                                                \
    _Float16* Hw = H[((ST) & 1) ^ 1];                                          \
    __syncthreads();                                                           \
    if ((ST) < 15) PF_LOAD(PFL, ts_ + 1);                                      \
    const bool hasX = (ts_ >= 0);                                              \
    const unsigned long long wm =                                              \
        ((ST) < 15 && ts_ + 1 >= 0) ? dmask[ts_ + 1] : 0ULL;                   \
    _Pragma("unroll") for (int m = 0; m < 2; ++m) {                            \
      const int mt = mg * 2 + m;                                               \
      const int rowA = mt * 16 + lr;                                           \
      half8 afr[4];                                                            \
      _Pragma("unroll") for (int kt = 0; kt < 4; ++kt)                         \
        afr[kt] = *(const half8*)(Hr + rowA * 128 +                            \
                                  ((kt * 32 + lg * 8) ^ ((rowA & 7) << 3)));   \
      f32x4 acc[4];                                                            \
      if (hasX) {                                                              \
        _Pragma("unroll") for (int ty = 0; ty < 4; ++ty) {                     \
          half4 p = PFU[ty][m];                                                \
          acc[ty][0] = (float)p[0]; acc[ty][1] = (float)p[1];                  \
          acc[ty][2] = (float)p[2]; acc[ty][3] = (float)p[3];                  \
        }                                                                      \
      } else {                                                                 \
        _Pragma("unroll") for (int ty = 0; ty < 4; ++ty) {                     \
          acc[ty][0] = b0[ty]; acc[ty][1] = b0[ty];                            \
          acc[ty][2] = b0[ty]; acc[ty][3] = b0[ty];                            \
        }                                                                      \
      }                                                                        \
      _Pragma("unroll") for (int ty = 0; ty < 4; ++ty)                         \
        _Pragma("unroll") for (int kt = 0; kt < 4; ++kt)                       \
          acc[ty] = MFMA(afr[kt], Wf[kt][ty], acc[ty]);                        \
      _Pragma("unroll") for (int r = 0; r < 4; ++r) {                          \
        const int s_ = mt * 16 + lg * 4 + r;                                   \
        const bool d = (wm >> s_) & 1ULL;                                      \
        float iv = sigf(acc[0][r]);                                            \
        float fv = sigf(acc[1][r]);                                            \
        float gv = tanhff(acc[2][r]);                                          \
        float ov = sigf(acc[3][r]);                                            \
        float cn = fmaf(fv, cc[m][r], iv * gv);                                \
        float hn = ov * tanhff(cn);                                            \
        cc[m][r] = d ? 0.f : cn;                                               \
        Hw[s_ * 128 + ((wc * 16 + lr) ^ ((s_ & 7) << 3))] =                    \
            (_Float16)(d ? 0.f : hn);                                          \
      }                                                                        \
    }                                                                          \
  } while (0)

  PF_LOAD(pfA, t - 15);       // prefetch step 0
  for (int s2 = 0; s2 < 8; ++s2) {
    LSTM_STEP(2 * s2,     pfA, pfB);
    LSTM_STEP(2 * s2 + 1, pfB, pfA);
  }
#undef LSTM_STEP
#undef PF_LOAD
  __syncthreads();

  // readout: out = h_final @ row_^T + rob  (h_final in H[0] after st=15)
  half8 R[4];
  #pragma unroll
  for (int kt = 0; kt < 4; ++kt)
    R[kt] = cvt8(row_ + (wc * 16 + lr) * 128 + kt * 32 + lg * 8);
  float rb2 = rob[wc * 16 + lr];
  #pragma unroll
  for (int m = 0; m < 2; ++m) {
    const int mt = mg * 2 + m;
    const int row = mt * 16 + lr;
    f32x4 acc; acc[0] = rb2; acc[1] = rb2; acc[2] = rb2; acc[3] = rb2;
    #pragma unroll
    for (int kt = 0; kt < 4; ++kt) {
      half8 a = *(const half8*)(H[0] + row * 128 + ((kt * 32 + lg * 8) ^ ((row & 7) << 3)));
      acc = MFMA(a, R[kt], acc);
    }
    #pragma unroll
    for (int r = 0; r < 4; ++r) {
      int s = mt * 16 + lg * 4 + r;
      out[(size_t)(t * 64 + s) * 128 + wc * 16 + lr] = acc[r];
    }
  }
}

extern "C" void kernel_launch(void* const* d_in, const int* in_sizes, int n_in,
                              void* d_out, int out_size, void* d_ws, size_t ws_size,
                              hipStream_t stream) {
  const float* inp = (const float*)d_in[0];
  const void*  don = d_in[1];
  const float* c1w = (const float*)d_in[2];
  const float* c1b = (const float*)d_in[3];
  const float* c2w = (const float*)d_in[4];
  const float* c2b = (const float*)d_in[5];
  const float* c3w = (const float*)d_in[6];
  const float* c3b = (const float*)d_in[7];
  const float* riw = (const float*)d_in[8];
  const float* rib = (const float*)d_in[9];
  const float* wih = (const float*)d_in[10];
  const float* whh = (const float*)d_in[11];
  const float* bih = (const float*)d_in[12];
  const float* bhh = (const float*)d_in[13];
  const float* row_ = (const float*)d_in[14];
  const float* rob = (const float*)d_in[15];

  unsigned long long* dmask = (unsigned long long*)d_ws;     // 2 KB
  _Float16* xgh = (_Float16*)((char*)d_ws + 16384);          // 16.8 MB f16

  (void)hipFuncSetAttribute((const void*)k_conv,
                            hipFuncAttributeMaxDynamicSharedMemorySize, 61952);

  k_done<<<256, 256, 0, stream>>>((const unsigned char*)don, dmask);
  k_conv<<<512, 512, 61952, stream>>>(inp, c1w, c1b, c2w, c2b, c3w, c3b,
                                      riw, rib, wih, bih, bhh, xgh);
  k_lstm<<<256, 1024, 0, stream>>>(whh, bih, bhh, xgh, dmask, row_, rob,
                                   (float*)d_out);
}

// Round 9
// 308.519 us; speedup vs baseline: 1.3663x; 1.2386x over previous
//
#include <hip/hip_runtime.h>

typedef _Float16 half8 __attribute__((ext_vector_type(8)));
typedef _Float16 half4 __attribute__((ext_vector_type(4)));
typedef float f32x4 __attribute__((ext_vector_type(4)));

__device__ __forceinline__ float eluf(float x)   { return x > 0.f ? x : __expf(x) - 1.f; }
__device__ __forceinline__ float sigf(float x)   { return 1.f / (1.f + __expf(-x)); }
__device__ __forceinline__ float tanhff(float x) { float e = __expf(2.f * x); return 1.f - 2.f / (e + 1.f); }

__device__ __forceinline__ half8 cvt8(const float* __restrict__ p) {
  f32x4 v0 = *(const f32x4*)p;
  f32x4 v1 = *(const f32x4*)(p + 4);
  half8 r;
  r[0] = (_Float16)v0[0]; r[1] = (_Float16)v0[1]; r[2] = (_Float16)v0[2]; r[3] = (_Float16)v0[3];
  r[4] = (_Float16)v1[0]; r[5] = (_Float16)v1[1]; r[6] = (_Float16)v1[2]; r[7] = (_Float16)v1[3];
  return r;
}
#define MFMA(a, b, c) __builtin_amdgcn_mfma_f32_16x16x32_f16(a, b, c, 0, 0, 0)

// ---------------- done normalize -> per-t u64 bitmask (parallel) ------------
__global__ __launch_bounds__(256) void k_done(const unsigned char* __restrict__ raw,
                                              unsigned long long* __restrict__ dmask) {
  __shared__ int f0, f1;
  if (threadIdx.x == 0) { f0 = 0; f1 = 0; }
  __syncthreads();
  int l0 = 0, l1 = 0;
  for (int i = threadIdx.x; i < 16384; i += 256)
    if (raw[i]) { if (i & 3) l0 = 1; else l1 = 1; }
  if (l0) atomicOr(&f0, 1);
  if (l1) atomicOr(&f1, 1);
  __syncthreads();
  int mode = (f0 && f1) ? 0 : (f1 ? 1 : (f0 ? 2 : 0));
  const int t = blockIdx.x;
  if (threadIdx.x < 64) {
    int i = t * 64 + threadIdx.x;
    bool v;
    if (mode == 0)      v = raw[i] != 0;
    else if (mode == 1) v = ((const int*)raw)[i] != 0;
    else                v = (((const float*)raw)[i] != 0.f);
    unsigned long long m = __ballot(v);
    if (threadIdx.x == 0) dmask[t] = m;
  }
}

// ---------------- conv stack + readin + xgates (all-MFMA, from R8) ----------
__global__ __launch_bounds__(512, 4) void k_conv(
    const float* __restrict__ inp,
    const float* __restrict__ c1w, const float* __restrict__ c1b,
    const float* __restrict__ c2w, const float* __restrict__ c2b,
    const float* __restrict__ c3w, const float* __restrict__ c3b,
    const float* __restrict__ riw, const float* __restrict__ rib,
    const float* __restrict__ wih, const float* __restrict__ bih,
    const float* __restrict__ bhh,
    _Float16* __restrict__ xgh)   // [256 t][512 gate][64 b] f16
{
  extern __shared__ char L[];
  unsigned*  LUT32 = (unsigned*)L;              // [32] u32, 128 B
  _Float16*  ic1   = (_Float16*)(L + 128);      // [256][32] f16 swz, 16384 B
  _Float16*  a1t   = (_Float16*)(L + 16512);    // [16][1160] f16, 37120 B
  _Float16*  a2    = (_Float16*)(L + 53632);    // [32][128] f16 swz, 8192 B
  _Float16*  ft    = (_Float16*)(L + 128);      // overlay (ic1/a1t dead)
  _Float16*  yb    = (_Float16*)(L + 8320);     // overlay

  const int tid  = threadIdx.x;
  const int lane = tid & 63;
  const int wv   = tid >> 6;        // 0..7
  const int lr   = lane & 15;
  const int lg   = lane >> 4;
  const int t    = blockIdx.x >> 1;
  const int bh   = blockIdx.x & 1;

  const int ntl  = wv & 1;          // n-tile for conv1/conv2 (o = ntl*16+lr)
  const int mq   = wv >> 1;         // m-group
  const int o1   = ntl * 16 + lr;

  if (tid < 32) {
    unsigned v = 0xFFFFFFFFu;
    if (tid < 27) { int c = tid / 9, r9 = tid % 9; v = (unsigned)(c | ((r9 / 3) << 8) | ((r9 % 3) << 16)); }
    LUT32[tid] = v;
  }

  half8 B1;
  #pragma unroll
  for (int e = 0; e < 8; ++e) {
    int k = lg * 8 + e;
    B1[e] = (_Float16)((k < 27) ? c1w[o1 * 27 + k] : 0.f);
  }
  const float b1o = c1b[o1];

  half8 B2t[9];
  #pragma unroll
  for (int tap = 0; tap < 9; ++tap) {
    half8 b;
    #pragma unroll
    for (int e = 0; e < 8; ++e)
      b[e] = (_Float16)c2w[o1 * 288 + (lg * 8 + e) * 9 + tap];
    B2t[tap] = b;
  }
  const float b2o = c2b[o1];

  for (int ch = 0; ch < 2; ++ch) {        // 2 chunks x 16 samples
    __syncthreads();
    for (int i = tid; i < 18560 / 2; i += 512) ((unsigned*)a1t)[i] = 0u;
    {
      const size_t n0 = (size_t)(t * 64 + bh * 32 + ch * 16) * 147;
      #pragma unroll
      for (int j = 0; j < 16; ++j) {
        int e = tid + j * 512;            // 0..8191
        int row = e >> 5, k = e & 31;
        int s = row >> 4, pos = row & 15;
        int p = pos >> 2, q = pos & 3;
        unsigned lut = LUT32[k];
        float v = 0.f;
        if (lut != 0xFFFFFFFFu) {
          int c = lut & 0xFF, dp = (lut >> 8) & 0xFF, dq = (lut >> 16) & 0xFF;
          int pp = 2 * p + dp - 1, qq = 2 * q + dq - 1;
          if ((unsigned)pp < 7u && (unsigned)qq < 7u)
            v = inp[n0 + s * 147 + qq * 21 + pp * 3 + c];
        }
        ic1[row * 32 + (k ^ ((row & 3) << 3))] = (_Float16)v;
      }
    }
    __syncthreads();
    #pragma unroll
    for (int mi = 0; mi < 4; ++mi) {
      const int mtile = mq * 4 + mi;
      const int rowA  = mtile * 16 + lr;
      half8 a = *(const half8*)(ic1 + rowA * 32 + ((lg * 8) ^ ((rowA & 3) << 3)));
      f32x4 acc; acc[0] = b1o; acc[1] = b1o; acc[2] = b1o; acc[3] = b1o;
      acc = MFMA(a, B1, acc);
      #pragma unroll
      for (int r = 0; r < 4; ++r) {
        int m1 = mtile * 16 + lg * 4 + r;
        int s = m1 >> 4, pos = m1 & 15;
        int p = pos >> 2, q = pos & 3;
        int xy = (p + 1) * 6 + (q + 1);
        a1t[s * 1160 + xy * 32 + (o1 ^ ((xy & 3) << 3))] = (_Float16)eluf(acc[r]);
      }
    }
    __syncthreads();
    {
      f32x4 acc; acc[0] = b2o; acc[1] = b2o; acc[2] = b2o; acc[3] = b2o;
      const int rowm = mq * 16 + lr;
      const int s2 = rowm >> 2, pos2 = rowm & 3;
      const int p2 = pos2 >> 1, q2 = pos2 & 1;
      #pragma unroll
      for (int tap = 0; tap < 9; ++tap) {
        const int dp = tap / 3, dq = tap % 3;
        const int xy2 = (2 * p2 + dp) * 6 + (2 * q2 + dq);
        half8 a = *(const half8*)(a1t + s2 * 1160 + xy2 * 32 + ((lg * 8) ^ ((xy2 & 3) << 3)));
        acc = MFMA(a, B2t[tap], acc);
      }
      #pragma unroll
      for (int r = 0; r < 4; ++r) {
        int m = mq * 16 + lg * 4 + r;
        int s2w = m >> 2, pos = m & 3;
        int arow = ch * 16 + s2w;
        int col = o1 * 4 + pos;
        a2[arow * 128 + (col ^ ((arow & 7) << 3))] = (_Float16)eluf(acc[r]);
      }
    }
  }
  __syncthreads();

  // conv3 GEMM: M=32, K=128, N=128
  {
    half8 B3[4];
    #pragma unroll
    for (int kt = 0; kt < 4; ++kt) {
      half8 b;
      #pragma unroll
      for (int e = 0; e < 8; ++e) {
        int k = kt * 32 + lg * 8 + e;
        int i = k >> 2, pos = k & 3;
        int widx = 4 + (pos >> 1) * 3 + (pos & 1);
        b[e] = (_Float16)c3w[(wv * 16 + lr) * 288 + i * 9 + widx];
      }
      B3[kt] = b;
    }
    float bb = c3b[wv * 16 + lr];
    #pragma unroll
    for (int mt = 0; mt < 2; ++mt) {
      f32x4 acc; acc[0] = bb; acc[1] = bb; acc[2] = bb; acc[3] = bb;
      const int row = mt * 16 + lr;
      #pragma unroll
      for (int kt = 0; kt < 4; ++kt) {
        half8 a = *(const half8*)(a2 + row * 128 + ((kt * 32 + lg * 8) ^ ((row & 7) << 3)));
        acc = MFMA(a, B3[kt], acc);
      }
      #pragma unroll
      for (int r = 0; r < 4; ++r) {
        int m = mt * 16 + lg * 4 + r;
        ft[m * 128 + ((wv * 16 + lr) ^ ((m & 7) << 3))] = (_Float16)eluf(acc[r]);
      }
    }
  }
  __syncthreads();

  // GEMM1: y = ft @ riw^T + rib
  {
    half8 R1[4];
    #pragma unroll
    for (int kt = 0; kt < 4; ++kt)
      R1[kt] = cvt8(riw + (wv * 16 + lr) * 128 + kt * 32 + lg * 8);
    float bb = rib[wv * 16 + lr];
    #pragma unroll
    for (int mt = 0; mt < 2; ++mt) {
      f32x4 acc; acc[0] = bb; acc[1] = bb; acc[2] = bb; acc[3] = bb;
      const int row = mt * 16 + lr;
      #pragma unroll
      for (int kt = 0; kt < 4; ++kt) {
        half8 a = *(const half8*)(ft + row * 128 + ((kt * 32 + lg * 8) ^ ((row & 7) << 3)));
        acc = MFMA(a, R1[kt], acc);
      }
      #pragma unroll
      for (int r = 0; r < 4; ++r) {
        int m = mt * 16 + lg * 4 + r;
        yb[m * 128 + ((wv * 16 + lr) ^ ((m & 7) << 3))] = (_Float16)acc[r];
      }
    }
  }
  __syncthreads();

  // GEMM2: xg = y @ wih^T + (bih + bhh)
  {
    half8 W2f[4][4];
    float bg[4];
    #pragma unroll
    for (int ty = 0; ty < 4; ++ty) {
      int g = ty * 128 + wv * 16 + lr;
      bg[ty] = bih[g] + bhh[g];
      #pragma unroll
      for (int kt = 0; kt < 4; ++kt)
        W2f[kt][ty] = cvt8(wih + g * 128 + kt * 32 + lg * 8);
    }
    #pragma unroll
    for (int mt = 0; mt < 2; ++mt) {
      const int row = mt * 16 + lr;
      half8 a[4];
      #pragma unroll
      for (int kt = 0; kt < 4; ++kt)
        a[kt] = *(const half8*)(yb + row * 128 + ((kt * 32 + lg * 8) ^ ((row & 7) << 3)));
      #pragma unroll
      for (int ty = 0; ty < 4; ++ty) {
        f32x4 acc; acc[0] = bg[ty]; acc[1] = bg[ty]; acc[2] = bg[ty]; acc[3] = bg[ty];
        #pragma unroll
        for (int kt = 0; kt < 4; ++kt) acc = MFMA(a[kt], W2f[kt][ty], acc);
        int g = ty * 128 + wv * 16 + lr;
        half4 h4;
        h4[0] = (_Float16)acc[0]; h4[1] = (_Float16)acc[1];
        h4[2] = (_Float16)acc[2]; h4[3] = (_Float16)acc[3];
        *(half4*)(xgh + ((size_t)t * 512 + g) * 64 + bh * 32 + mt * 16 + lg * 4) = h4;
      }
    }
  }
}

// ---------------- windowed LSTM (16 steps, MFMA) + readout ------------------
// block = (t, b-half) = 32 samples, 512 thr / 8 waves; 2 blocks/CU (grid 512,
// 16 KB LDS, VGPR cap 128 honored — R4 precedent compiles at 64 arch VGPR).
// Swizzle for round-robin-singles dispatch: XCD x gets both halves of
// t in [32x, 32x+32) -> 2.1 MB f16 window per XCD L2. No prefetch (R6: null).
__global__ __launch_bounds__(512, 4) void k_lstm(
    const float* __restrict__ whh, const float* __restrict__ bih,
    const float* __restrict__ bhh, const _Float16* __restrict__ xgh,
    const unsigned long long* __restrict__ dmask,
    const float* __restrict__ row_, const float* __restrict__ rob,
    float* __restrict__ out)
{
  __shared__ _Float16 H[2][32 * 128];   // 16 KB, XOR-swizzled rows

  const int tid  = threadIdx.x;
  const int lane = tid & 63;
  const int wv   = tid >> 6;            // cell group: cells wv*16 + lr
  const int lr   = lane & 15, lg = lane >> 4;
  const int xcd  = blockIdx.x & 7;
  const int j    = blockIdx.x >> 3;     // 0..63 per XCD
  const int t    = (xcd << 5) + (j >> 1);
  const int bh   = j & 1;
  const int bbase = bh * 32;

  // w_hh B-frags: [kt][ty], gate g = ty*128 + wv*16 + lr
  half8 Wf[4][4];
  float b0[4];
  #pragma unroll
  for (int ty = 0; ty < 4; ++ty) {
    int g = ty * 128 + wv * 16 + lr;
    b0[ty] = bih[g] + bhh[g];
    #pragma unroll
    for (int kt = 0; kt < 4; ++kt)
      Wf[kt][ty] = cvt8(whh + g * 128 + kt * 32 + lg * 8);
  }

  for (int i = tid; i < 32 * 128 / 2; i += 512) ((unsigned*)H[0])[i] = 0u;

  float cc[2][4];   // [mt][r]: local sample mt*16 + lg*4 + r, cell wv*16+lr
  #pragma unroll
  for (int mt = 0; mt < 2; ++mt)
    #pragma unroll
    for (int r = 0; r < 4; ++r) cc[mt][r] = 0.f;

  for (int st = 0; st < 16; ++st) {
    const int ts = t + st - 15;
    _Float16* Hr = H[st & 1];
    _Float16* Hw = H[(st & 1) ^ 1];
    __syncthreads();
    const bool hasX = (ts >= 0);
    const unsigned long long wm =
        (st < 15 && ts + 1 >= 0) ? dmask[ts + 1] : 0ULL;
    const _Float16* xb = xgh + (size_t)ts * 32768 + bbase;
    #pragma unroll
    for (int mt = 0; mt < 2; ++mt) {
      const int rowA = mt * 16 + lr;
      half8 afr[4];
      #pragma unroll
      for (int kt = 0; kt < 4; ++kt)
        afr[kt] = *(const half8*)(Hr + rowA * 128 + ((kt * 32 + lg * 8) ^ ((rowA & 7) << 3)));
      f32x4 acc[4];
      if (hasX) {
        #pragma unroll
        for (int ty = 0; ty < 4; ++ty) {
          half4 p = *(const half4*)(xb + (ty * 128 + wv * 16 + lr) * 64 + mt * 16 + lg * 4);
          acc[ty][0] = (float)p[0]; acc[ty][1] = (float)p[1];
          acc[ty][2] = (float)p[2]; acc[ty][3] = (float)p[3];
        }
      } else {
        #pragma unroll
        for (int ty = 0; ty < 4; ++ty) {
          acc[ty][0] = b0[ty]; acc[ty][1] = b0[ty]; acc[ty][2] = b0[ty]; acc[ty][3] = b0[ty];
        }
      }
      #pragma unroll
      for (int ty = 0; ty < 4; ++ty)
        #pragma unroll
        for (int kt = 0; kt < 4; ++kt)
          acc[ty] = MFMA(afr[kt], Wf[kt][ty], acc[ty]);
      #pragma unroll
      for (int r = 0; r < 4; ++r) {
        const int s_ = mt * 16 + lg * 4 + r;        // local sample 0..31
        const bool d = (wm >> (bbase + s_)) & 1ULL;
        float iv = sigf(acc[0][r]);
        float fv = sigf(acc[1][r]);
        float gv = tanhff(acc[2][r]);
        float ov = sigf(acc[3][r]);
        float cn = fmaf(fv, cc[mt][r], iv * gv);
        float hn = ov * tanhff(cn);
        cc[mt][r] = d ? 0.f : cn;
        Hw[s_ * 128 + ((wv * 16 + lr) ^ ((s_ & 7) << 3))] = (_Float16)(d ? 0.f : hn);
      }
    }
  }
  __syncthreads();

  // readout: out = h_final @ row_^T + rob  (h_final in H[0] after st=15)
  half8 R[4];
  #pragma unroll
  for (int kt = 0; kt < 4; ++kt)
    R[kt] = cvt8(row_ + (wv * 16 + lr) * 128 + kt * 32 + lg * 8);
  float rb2 = rob[wv * 16 + lr];
  #pragma unroll
  for (int mt = 0; mt < 2; ++mt) {
    const int row = mt * 16 + lr;
    f32x4 acc; acc[0] = rb2; acc[1] = rb2; acc[2] = rb2; acc[3] = rb2;
    #pragma unroll
    for (int kt = 0; kt < 4; ++kt) {
      half8 a = *(const half8*)(H[0] + row * 128 + ((kt * 32 + lg * 8) ^ ((row & 7) << 3)));
      acc = MFMA(a, R[kt], acc);
    }
    #pragma unroll
    for (int r = 0; r < 4; ++r) {
      int s = mt * 16 + lg * 4 + r;
      out[(size_t)(t * 64 + bbase + s) * 128 + wv * 16 + lr] = acc[r];
    }
  }
}

extern "C" void kernel_launch(void* const* d_in, const int* in_sizes, int n_in,
                              void* d_out, int out_size, void* d_ws, size_t ws_size,
                              hipStream_t stream) {
  const float* inp = (const float*)d_in[0];
  const void*  don = d_in[1];
  const float* c1w = (const float*)d_in[2];
  const float* c1b = (const float*)d_in[3];
  const float* c2w = (const float*)d_in[4];
  const float* c2b = (const float*)d_in[5];
  const float* c3w = (const float*)d_in[6];
  const float* c3b = (const float*)d_in[7];
  const float* riw = (const float*)d_in[8];
  const float* rib = (const float*)d_in[9];
  const float* wih = (const float*)d_in[10];
  const float* whh = (const float*)d_in[11];
  const float* bih = (const float*)d_in[12];
  const float* bhh = (const float*)d_in[13];
  const float* row_ = (const float*)d_in[14];
  const float* rob = (const float*)d_in[15];

  unsigned long long* dmask = (unsigned long long*)d_ws;     // 2 KB
  _Float16* xgh = (_Float16*)((char*)d_ws + 16384);          // 16.8 MB f16

  (void)hipFuncSetAttribute((const void*)k_conv,
                            hipFuncAttributeMaxDynamicSharedMemorySize, 61952);

  k_done<<<256, 256, 0, stream>>>((const unsigned char*)don, dmask);
  k_conv<<<512, 512, 61952, stream>>>(inp, c1w, c1b, c2w, c2b, c3w, c3b,
                                      riw, rib, wih, bih, bhh, xgh);
  k_lstm<<<512, 512, 0, stream>>>(whh, bih, bhh, xgh, dmask, row_, rob,
                                  (float*)d_out);
}

// Round 10
// 225.362 us; speedup vs baseline: 1.8704x; 1.3690x over previous
//
#include <hip/hip_runtime.h>

typedef _Float16 half8 __attribute__((ext_vector_type(8)));
typedef _Float16 half4 __attribute__((ext_vector_type(4)));
typedef float f32x4 __attribute__((ext_vector_type(4)));

__device__ __forceinline__ float eluf(float x)   { return x > 0.f ? x : __expf(x) - 1.f; }
// fast sigmoid/tanh: v_rcp instead of IEEE fdiv (rel err ~1e-7, budget 4.5e-4)
__device__ __forceinline__ float sigf(float x) {
  return __builtin_amdgcn_rcpf(1.f + __expf(-x));
}
__device__ __forceinline__ float tanhff(float x) {
  return 1.f - 2.f * __builtin_amdgcn_rcpf(__expf(2.f * x) + 1.f);
}

__device__ __forceinline__ half8 cvt8(const float* __restrict__ p) {
  f32x4 v0 = *(const f32x4*)p;
  f32x4 v1 = *(const f32x4*)(p + 4);
  half8 r;
  r[0] = (_Float16)v0[0]; r[1] = (_Float16)v0[1]; r[2] = (_Float16)v0[2]; r[3] = (_Float16)v0[3];
  r[4] = (_Float16)v1[0]; r[5] = (_Float16)v1[1]; r[6] = (_Float16)v1[2]; r[7] = (_Float16)v1[3];
  return r;
}
#define MFMA(a, b, c) __builtin_amdgcn_mfma_f32_16x16x32_f16(a, b, c, 0, 0, 0)

// ---------------- done normalize -> per-t u64 bitmask (parallel) ------------
__global__ __launch_bounds__(256) void k_done(const unsigned char* __restrict__ raw,
                                              unsigned long long* __restrict__ dmask) {
  __shared__ int f0, f1;
  if (threadIdx.x == 0) { f0 = 0; f1 = 0; }
  __syncthreads();
  int l0 = 0, l1 = 0;
  for (int i = threadIdx.x; i < 16384; i += 256)
    if (raw[i]) { if (i & 3) l0 = 1; else l1 = 1; }
  if (l0) atomicOr(&f0, 1);
  if (l1) atomicOr(&f1, 1);
  __syncthreads();
  int mode = (f0 && f1) ? 0 : (f1 ? 1 : (f0 ? 2 : 0));
  const int t = blockIdx.x;
  if (threadIdx.x < 64) {
    int i = t * 64 + threadIdx.x;
    bool v;
    if (mode == 0)      v = raw[i] != 0;
    else if (mode == 1) v = ((const int*)raw)[i] != 0;
    else                v = (((const float*)raw)[i] != 0.f);
    unsigned long long m = __ballot(v);
    if (threadIdx.x == 0) dmask[t] = m;
  }
}

// ---------------- conv stack + readin + xgates (all-MFMA) -------------------
// block = (t, b-half) = 32 samples, 512 threads / 8 waves; 60.5 KB LDS.
// launch_bounds(512,3): VGPR cap 170 — avoids the min-waves=4 VGPR-64 spill.
__global__ __launch_bounds__(512, 3) void k_conv(
    const float* __restrict__ inp,
    const float* __restrict__ c1w, const float* __restrict__ c1b,
    const float* __restrict__ c2w, const float* __restrict__ c2b,
    const float* __restrict__ c3w, const float* __restrict__ c3b,
    const float* __restrict__ riw, const float* __restrict__ rib,
    const float* __restrict__ wih, const float* __restrict__ bih,
    const float* __restrict__ bhh,
    _Float16* __restrict__ xgh)   // [256 t][512 gate][64 b] f16
{
  extern __shared__ char L[];
  unsigned*  LUT32 = (unsigned*)L;              // [32] u32, 128 B
  _Float16*  ic1   = (_Float16*)(L + 128);      // [256][32] f16 swz, 16384 B
  _Float16*  a1t   = (_Float16*)(L + 16512);    // [16][1160] f16, 37120 B
  _Float16*  a2    = (_Float16*)(L + 53632);    // [32][128] f16 swz, 8192 B
  _Float16*  ft    = (_Float16*)(L + 128);      // overlay (ic1/a1t dead)
  _Float16*  yb    = (_Float16*)(L + 8320);     // overlay

  const int tid  = threadIdx.x;
  const int lane = tid & 63;
  const int wv   = tid >> 6;        // 0..7
  const int lr   = lane & 15;
  const int lg   = lane >> 4;
  const int t    = blockIdx.x >> 1;
  const int bh   = blockIdx.x & 1;

  const int ntl  = wv & 1;          // n-tile for conv1/conv2 (o = ntl*16+lr)
  const int mq   = wv >> 1;         // m-group
  const int o1   = ntl * 16 + lr;

  if (tid < 32) {
    unsigned v = 0xFFFFFFFFu;
    if (tid < 27) { int c = tid / 9, r9 = tid % 9; v = (unsigned)(c | ((r9 / 3) << 8) | ((r9 % 3) << 16)); }
    LUT32[tid] = v;
  }

  half8 B1;
  #pragma unroll
  for (int e = 0; e < 8; ++e) {
    int k = lg * 8 + e;
    B1[e] = (_Float16)((k < 27) ? c1w[o1 * 27 + k] : 0.f);
  }
  const float b1o = c1b[o1];

  half8 B2t[9];
  #pragma unroll
  for (int tap = 0; tap < 9; ++tap) {
    half8 b;
    #pragma unroll
    for (int e = 0; e < 8; ++e)
      b[e] = (_Float16)c2w[o1 * 288 + (lg * 8 + e) * 9 + tap];
    B2t[tap] = b;
  }
  const float b2o = c2b[o1];

  for (int ch = 0; ch < 2; ++ch) {        // 2 chunks x 16 samples
    __syncthreads();
    for (int i = tid; i < 18560 / 2; i += 512) ((unsigned*)a1t)[i] = 0u;
    {
      const size_t n0 = (size_t)(t * 64 + bh * 32 + ch * 16) * 147;
      #pragma unroll
      for (int j = 0; j < 16; ++j) {
        int e = tid + j * 512;            // 0..8191
        int row = e >> 5, k = e & 31;
        int s = row >> 4, pos = row & 15;
        int p = pos >> 2, q = pos & 3;
        unsigned lut = LUT32[k];
        float v = 0.f;
        if (lut != 0xFFFFFFFFu) {
          int c = lut & 0xFF, dp = (lut >> 8) & 0xFF, dq = (lut >> 16) & 0xFF;
          int pp = 2 * p + dp - 1, qq = 2 * q + dq - 1;
          if ((unsigned)pp < 7u && (unsigned)qq < 7u)
            v = inp[n0 + s * 147 + qq * 21 + pp * 3 + c];
        }
        ic1[row * 32 + (k ^ ((row & 3) << 3))] = (_Float16)v;
      }
    }
    __syncthreads();
    #pragma unroll
    for (int mi = 0; mi < 4; ++mi) {
      const int mtile = mq * 4 + mi;
      const int rowA  = mtile * 16 + lr;
      half8 a = *(const half8*)(ic1 + rowA * 32 + ((lg * 8) ^ ((rowA & 3) << 3)));
      f32x4 acc; acc[0] = b1o; acc[1] = b1o; acc[2] = b1o; acc[3] = b1o;
      acc = MFMA(a, B1, acc);
      #pragma unroll
      for (int r = 0; r < 4; ++r) {
        int m1 = mtile * 16 + lg * 4 + r;
        int s = m1 >> 4, pos = m1 & 15;
        int p = pos >> 2, q = pos & 3;
        int xy = (p + 1) * 6 + (q + 1);
        a1t[s * 1160 + xy * 32 + (o1 ^ ((xy & 3) << 3))] = (_Float16)eluf(acc[r]);
      }
    }
    __syncthreads();
    {
      f32x4 acc; acc[0] = b2o; acc[1] = b2o; acc[2] = b2o; acc[3] = b2o;
      const int rowm = mq * 16 + lr;
      const int s2 = rowm >> 2, pos2 = rowm & 3;
      const int p2 = pos2 >> 1, q2 = pos2 & 1;
      #pragma unroll
      for (int tap = 0; tap < 9; ++tap) {
        const int dp = tap / 3, dq = tap % 3;
        const int xy2 = (2 * p2 + dp) * 6 + (2 * q2 + dq);
        half8 a = *(const half8*)(a1t + s2 * 1160 + xy2 * 32 + ((lg * 8) ^ ((xy2 & 3) << 3)));
        acc = MFMA(a, B2t[tap], acc);
      }
      #pragma unroll
      for (int r = 0; r < 4; ++r) {
        int m = mq * 16 + lg * 4 + r;
        int s2w = m >> 2, pos = m & 3;
        int arow = ch * 16 + s2w;
        int col = o1 * 4 + pos;
        a2[arow * 128 + (col ^ ((arow & 7) << 3))] = (_Float16)eluf(acc[r]);
      }
    }
  }
  __syncthreads();

  // conv3 GEMM: M=32, K=128, N=128
  {
    half8 B3[4];
    #pragma unroll
    for (int kt = 0; kt < 4; ++kt) {
      half8 b;
      #pragma unroll
      for (int e = 0; e < 8; ++e) {
        int k = kt * 32 + lg * 8 + e;
        int i = k >> 2, pos = k & 3;
        int widx = 4 + (pos >> 1) * 3 + (pos & 1);
        b[e] = (_Float16)c3w[(wv * 16 + lr) * 288 + i * 9 + widx];
      }
      B3[kt] = b;
    }
    float bb = c3b[wv * 16 + lr];
    #pragma unroll
    for (int mt = 0; mt < 2; ++mt) {
      f32x4 acc; acc[0] = bb; acc[1] = bb; acc[2] = bb; acc[3] = bb;
      const int row = mt * 16 + lr;
      #pragma unroll
      for (int kt = 0; kt < 4; ++kt) {
        half8 a = *(const half8*)(a2 + row * 128 + ((kt * 32 + lg * 8) ^ ((row & 7) << 3)));
        acc = MFMA(a, B3[kt], acc);
      }
      #pragma unroll
      for (int r = 0; r < 4; ++r) {
        int m = mt * 16 + lg * 4 + r;
        ft[m * 128 + ((wv * 16 + lr) ^ ((m & 7) << 3))] = (_Float16)eluf(acc[r]);
      }
    }
  }
  __syncthreads();

  // GEMM1: y = ft @ riw^T + rib
  {
    half8 R1[4];
    #pragma unroll
    for (int kt = 0; kt < 4; ++kt)
      R1[kt] = cvt8(riw + (wv * 16 + lr) * 128 + kt * 32 + lg * 8);
    float bb = rib[wv * 16 + lr];
    #pragma unroll
    for (int mt = 0; mt < 2; ++mt) {
      f32x4 acc; acc[0] = bb; acc[1] = bb; acc[2] = bb; acc[3] = bb;
      const int row = mt * 16 + lr;
      #pragma unroll
      for (int kt = 0; kt < 4; ++kt) {
        half8 a = *(const half8*)(ft + row * 128 + ((kt * 32 + lg * 8) ^ ((row & 7) << 3)));
        acc = MFMA(a, R1[kt], acc);
      }
      #pragma unroll
      for (int r = 0; r < 4; ++r) {
        int m = mt * 16 + lg * 4 + r;
        yb[m * 128 + ((wv * 16 + lr) ^ ((m & 7) << 3))] = (_Float16)acc[r];
      }
    }
  }
  __syncthreads();

  // GEMM2: xg = y @ wih^T + (bih + bhh)
  {
    half8 W2f[4][4];
    float bg[4];
    #pragma unroll
    for (int ty = 0; ty < 4; ++ty) {
      int g = ty * 128 + wv * 16 + lr;
      bg[ty] = bih[g] + bhh[g];
      #pragma unroll
      for (int kt = 0; kt < 4; ++kt)
        W2f[kt][ty] = cvt8(wih + g * 128 + kt * 32 + lg * 8);
    }
    #pragma unroll
    for (int mt = 0; mt < 2; ++mt) {
      const int row = mt * 16 + lr;
      half8 a[4];
      #pragma unroll
      for (int kt = 0; kt < 4; ++kt)
        a[kt] = *(const half8*)(yb + row * 128 + ((kt * 32 + lg * 8) ^ ((row & 7) << 3)));
      #pragma unroll
      for (int ty = 0; ty < 4; ++ty) {
        f32x4 acc; acc[0] = bg[ty]; acc[1] = bg[ty]; acc[2] = bg[ty]; acc[3] = bg[ty];
        #pragma unroll
        for (int kt = 0; kt < 4; ++kt) acc = MFMA(a[kt], W2f[kt][ty], acc);
        int g = ty * 128 + wv * 16 + lr;
        half4 h4;
        h4[0] = (_Float16)acc[0]; h4[1] = (_Float16)acc[1];
        h4[2] = (_Float16)acc[2]; h4[3] = (_Float16)acc[3];
        *(half4*)(xgh + ((size_t)t * 512 + g) * 64 + bh * 32 + mt * 16 + lg * 4) = h4;
      }
    }
  }
}

// ---------------- windowed LSTM (16 steps, MFMA) + readout ------------------
// block = (t, b-half) = 32 samples, 512 thr / 8 waves, grid 512.
// launch_bounds(512,2): the ONLY setting measured spill-free (VGPR~124).
// At 124 VGPR the HW still grants 4 waves/SIMD -> 2 blocks/CU co-resident.
// XCD swizzle: XCD x owns both halves of t in [32x, 32x+32) (2.1 MB window).
__global__ __launch_bounds__(512, 2) void k_lstm(
    const float* __restrict__ whh, const float* __restrict__ bih,
    const float* __restrict__ bhh, const _Float16* __restrict__ xgh,
    const unsigned long long* __restrict__ dmask,
    const float* __restrict__ row_, const float* __restrict__ rob,
    float* __restrict__ out)
{
  __shared__ _Float16 H[2][32 * 128];   // 16 KB, XOR-swizzled rows

  const int tid  = threadIdx.x;
  const int lane = tid & 63;
  const int wv   = tid >> 6;            // cell group: cells wv*16 + lr
  const int lr   = lane & 15, lg = lane >> 4;
  const int xcd  = blockIdx.x & 7;
  const int j    = blockIdx.x >> 3;     // 0..63 per XCD
  const int t    = (xcd << 5) + (j >> 1);
  const int bh   = j & 1;
  const int bbase = bh * 32;

  // w_hh B-frags: [kt][ty], gate g = ty*128 + wv*16 + lr
  half8 Wf[4][4];
  float b0[4];
  #pragma unroll
  for (int ty = 0; ty < 4; ++ty) {
    int g = ty * 128 + wv * 16 + lr;
    b0[ty] = bih[g] + bhh[g];
    #pragma unroll
    for (int kt = 0; kt < 4; ++kt)
      Wf[kt][ty] = cvt8(whh + g * 128 + kt * 32 + lg * 8);
  }

  for (int i = tid; i < 32 * 128 / 2; i += 512) ((unsigned*)H[0])[i] = 0u;

  float cc[2][4];   // [mt][r]: local sample mt*16 + lg*4 + r, cell wv*16+lr
  #pragma unroll
  for (int mt = 0; mt < 2; ++mt)
    #pragma unroll
    for (int r = 0; r < 4; ++r) cc[mt][r] = 0.f;

  for (int st = 0; st < 16; ++st) {
    const int ts = t + st - 15;
    _Float16* Hr = H[st & 1];
    _Float16* Hw = H[(st & 1) ^ 1];
    __syncthreads();
    const bool hasX = (ts >= 0);
    const unsigned long long wm =
        (st < 15 && ts + 1 >= 0) ? dmask[ts + 1] : 0ULL;
    const _Float16* xb = xgh + (size_t)ts * 32768 + bbase;
    #pragma unroll
    for (int mt = 0; mt < 2; ++mt) {
      const int rowA = mt * 16 + lr;
      half8 afr[4];
      #pragma unroll
      for (int kt = 0; kt < 4; ++kt)
        afr[kt] = *(const half8*)(Hr + rowA * 128 + ((kt * 32 + lg * 8) ^ ((rowA & 7) << 3)));
      f32x4 acc[4];
      if (hasX) {
        #pragma unroll
        for (int ty = 0; ty < 4; ++ty) {
          half4 p = *(const half4*)(xb + (ty * 128 + wv * 16 + lr) * 64 + mt * 16 + lg * 4);
          acc[ty][0] = (float)p[0]; acc[ty][1] = (float)p[1];
          acc[ty][2] = (float)p[2]; acc[ty][3] = (float)p[3];
        }
      } else {
        #pragma unroll
        for (int ty = 0; ty < 4; ++ty) {
          acc[ty][0] = b0[ty]; acc[ty][1] = b0[ty]; acc[ty][2] = b0[ty]; acc[ty][3] = b0[ty];
        }
      }
      #pragma unroll
      for (int ty = 0; ty < 4; ++ty)
        #pragma unroll
        for (int kt = 0; kt < 4; ++kt)
          acc[ty] = MFMA(afr[kt], Wf[kt][ty], acc[ty]);
      #pragma unroll
      for (int r = 0; r < 4; ++r) {
        const int s_ = mt * 16 + lg * 4 + r;        // local sample 0..31
        const bool d = (wm >> (bbase + s_)) & 1ULL;
        float iv = sigf(acc[0][r]);
        float fv = sigf(acc[1][r]);
        float gv = tanhff(acc[2][r]);
        float ov = sigf(acc[3][r]);
        float cn = fmaf(fv, cc[mt][r], iv * gv);
        float hn = ov * tanhff(cn);
        cc[mt][r] = d ? 0.f : cn;
        Hw[s_ * 128 + ((wv * 16 + lr) ^ ((s_ & 7) << 3))] = (_Float16)(d ? 0.f : hn);
      }
    }
  }
  __syncthreads();

  // readout: out = h_final @ row_^T + rob  (h_final in H[0] after st=15)
  half8 R[4];
  #pragma unroll
  for (int kt = 0; kt < 4; ++kt)
    R[kt] = cvt8(row_ + (wv * 16 + lr) * 128 + kt * 32 + lg * 8);
  float rb2 = rob[wv * 16 + lr];
  #pragma unroll
  for (int mt = 0; mt < 2; ++mt) {
    const int row = mt * 16 + lr;
    f32x4 acc; acc[0] = rb2; acc[1] = rb2; acc[2] = rb2; acc[3] = rb2;
    #pragma unroll
    for (int kt = 0; kt < 4; ++kt) {
      half8 a = *(const half8*)(H[0] + row * 128 + ((kt * 32 + lg * 8) ^ ((row & 7) << 3)));
      acc = MFMA(a, R[kt], acc);
    }
    #pragma unroll
    for (int r = 0; r < 4; ++r) {
      int s = mt * 16 + lg * 4 + r;
      out[(size_t)(t * 64 + bbase + s) * 128 + wv * 16 + lr] = acc[r];
    }
  }
}

extern "C" void kernel_launch(void* const* d_in, const int* in_sizes, int n_in,
                              void* d_out, int out_size, void* d_ws, size_t ws_size,
                              hipStream_t stream) {
  const float* inp = (const float*)d_in[0];
  const void*  don = d_in[1];
  const float* c1w = (const float*)d_in[2];
  const float* c1b = (const float*)d_in[3];
  const float* c2w = (const float*)d_in[4];
  const float* c2b = (const float*)d_in[5];
  const float* c3w = (const float*)d_in[6];
  const float* c3b = (const float*)d_in[7];
  const float* riw = (const float*)d_in[8];
  const float* rib = (const float*)d_in[9];
  const float* wih = (const float*)d_in[10];
  const float* whh = (const float*)d_in[11];
  const float* bih = (const float*)d_in[12];
  const float* bhh = (const float*)d_in[13];
  const float* row_ = (const float*)d_in[14];
  const float* rob = (const float*)d_in[15];

  unsigned long long* dmask = (unsigned long long*)d_ws;     // 2 KB
  _Float16* xgh = (_Float16*)((char*)d_ws + 16384);          // 16.8 MB f16

  (void)hipFuncSetAttribute((const void*)k_conv,
                            hipFuncAttributeMaxDynamicSharedMemorySize, 61952);

  k_done<<<256, 256, 0, stream>>>((const unsigned char*)don, dmask);
  k_conv<<<512, 512, 61952, stream>>>(inp, c1w, c1b, c2w, c2b, c3w, c3b,
                                      riw, rib, wih, bih, bhh, xgh);
  k_lstm<<<512, 512, 0, stream>>>(whh, bih, bhh, xgh, dmask, row_, rob,
                                  (float*)d_out);
}